// Round 1
// baseline (505.602 us; speedup 1.0000x reference)
//
#include <hip/hip_runtime.h>

typedef float f32x4 __attribute__((ext_vector_type(4)));
typedef short s16x8 __attribute__((ext_vector_type(8)));

#define NPOS 4096
#define CD   256
#define NB   64
#define NBETA 512
#define NHID 512
#define PPB  16
#define NBLK 256
#define HTP  520  // padded hterm row stride in ushorts

__device__ __forceinline__ unsigned short f2bf(float x) {
    unsigned int u = __builtin_bit_cast(unsigned int, x);
    u += 0x7fffu + ((u >> 16) & 1u);
    return (unsigned short)(u >> 16);
}
__device__ __forceinline__ float bf2f(unsigned short h) {
    unsigned int u = ((unsigned int)h) << 16;
    return __builtin_bit_cast(float, u);
}

// ---------------------------------------------------------------------------
// Prep: hterm[b][beta] = h_t[b]·W_h_w[beta] + W_h_b[beta] + W_b[beta] (bf16)
//       wwb = bf16(W_w)  [512][256]
// ---------------------------------------------------------------------------
__global__ __launch_bounds__(512) void prep_kernel(
    const float* __restrict__ h_t, const float* __restrict__ W_h_w,
    const float* __restrict__ W_h_b, const float* __restrict__ W_w,
    const float* __restrict__ W_b,
    unsigned short* __restrict__ hws, unsigned short* __restrict__ wwb)
{
    const int blk = blockIdx.x;
    const int tid = threadIdx.x;
    if (blk < NB) {
        __shared__ float hrow[NHID];
        hrow[tid] = h_t[blk * NHID + tid];
        __syncthreads();
        const float* wr = W_h_w + tid * NHID;
        float acc = W_h_b[tid] + W_b[tid];
        #pragma unroll 4
        for (int h = 0; h < NHID; h += 4) {
            f32x4 wv = *(const f32x4*)(wr + h);
            acc += wv.x * hrow[h] + wv.y * hrow[h + 1] +
                   wv.z * hrow[h + 2] + wv.w * hrow[h + 3];
        }
        hws[blk * NBETA + tid] = f2bf(acc);
    } else {
        const int idx = ((blk - NB) * 512 + tid) * 8;
        f32x4 a = *(const f32x4*)(W_w + idx);
        f32x4 b = *(const f32x4*)(W_w + idx + 4);
        s16x8 pk;
        pk[0] = (short)f2bf(a.x); pk[1] = (short)f2bf(a.y);
        pk[2] = (short)f2bf(a.z); pk[3] = (short)f2bf(a.w);
        pk[4] = (short)f2bf(b.x); pk[5] = (short)f2bf(b.y);
        pk[6] = (short)f2bf(b.z); pk[7] = (short)f2bf(b.w);
        *(s16x8*)(wwb + idx) = pk;
    }
}

// ---------------------------------------------------------------------------
// Main: per block, 16 positions. Per position p:
//   U[beta][b] = W_w @ V_p (MFMA bf16), e[b] = sum_beta tanh(U+hterm)*bw
//   w = exp(e + beta_b);  cacc[c][b] += w*V;  lacc[b] += w
// Partials -> workspace; combine kernel normalizes.
// ---------------------------------------------------------------------------
__global__ __launch_bounds__(512, 2) void attn_main(
    const float* __restrict__ V,
    const unsigned short* __restrict__ wwb,
    const unsigned short* __restrict__ hws,
    const float* __restrict__ beta_w,
    const float* __restrict__ beta_b,
    float* __restrict__ num,
    float* __restrict__ lsum)
{
    __shared__ unsigned short Vt[2][32 * 64 * 8];  // [cb][b][8c] bf16, 2x32KB
    __shared__ unsigned short ht[64 * HTP];        // [b][beta] padded, 65KB
    __shared__ float ew[8][64];

    const int tid = threadIdx.x;
    const int l = tid & 63;   // lane
    const int w = tid >> 6;   // wave: beta slice [w*64, w*64+64)
    const int g = l >> 4;
    const int r = l & 15;

    // hterm -> LDS (padded rows)
    #pragma unroll
    for (int it = 0; it < 8; ++it) {
        int e = (it * 512 + tid) * 8;
        int row = e >> 9, col = e & 511;
        *(s16x8*)(&ht[row * HTP + col]) = *(const s16x8*)(hws + e);
    }

    // per-lane beta_w values for acc rows: beta = w*64 + m*16 + g*4 + q
    float bw[4][4];
    #pragma unroll
    for (int m = 0; m < 4; ++m) {
        f32x4 t = *(const f32x4*)(beta_w + w * 64 + m * 16 + g * 4);
        bw[m][0] = t.x; bw[m][1] = t.y; bw[m][2] = t.z; bw[m][3] = t.w;
    }
    const float bbias = beta_b[0];

    float cacc[32];
    #pragma unroll
    for (int i = 0; i < 32; ++i) cacc[i] = 0.f;
    float lacc = 0.f;

    const int p0 = blockIdx.x * PPB;
    const float* vbase = V + l;
    float nv[32];

    // prologue: stage position p0 into buffer 0
    {
        const float* vp = vbase + (long)p0 * (CD * NB);
        #pragma unroll
        for (int rr = 0; rr < 4; ++rr)
            #pragma unroll
            for (int j = 0; j < 8; ++j)
                nv[rr * 8 + j] = vp[(rr * 64 + w * 8 + j) * NB];
        #pragma unroll
        for (int rr = 0; rr < 4; ++rr) {
            s16x8 pk;
            #pragma unroll
            for (int j = 0; j < 8; ++j) pk[j] = (short)f2bf(nv[rr * 8 + j]);
            *(s16x8*)(&Vt[0][((rr * 8 + w) * 64 + l) * 8]) = pk;
        }
    }
    __syncthreads();

    for (int i = 0; i < PPB; ++i) {
        const int cur = i & 1;
        const unsigned short* vt = Vt[cur];
        const bool pf = (i + 1 < PPB);

        // issue next-position global loads early (hide HBM under MFMA)
        if (pf) {
            const float* vp = vbase + (long)(p0 + i + 1) * (CD * NB);
            #pragma unroll
            for (int rr = 0; rr < 4; ++rr)
                #pragma unroll
                for (int j = 0; j < 8; ++j)
                    nv[rr * 8 + j] = vp[(rr * 64 + w * 8 + j) * NB];
        }

        f32x4 acc[4][4];
        #pragma unroll
        for (int m = 0; m < 4; ++m)
            #pragma unroll
            for (int n = 0; n < 4; ++n)
                acc[m][n] = (f32x4){0.f, 0.f, 0.f, 0.f};

        // U = W_w @ V_p : M=512(beta, wave-split) N=64(b) K=256(c)
        #pragma unroll
        for (int ks = 0; ks < 8; ++ks) {
            s16x8 af[4], bf[4];
            #pragma unroll
            for (int m = 0; m < 4; ++m)
                af[m] = *(const s16x8*)(wwb + (w * 64 + m * 16 + r) * CD + ks * 32 + g * 8);
            #pragma unroll
            for (int n = 0; n < 4; ++n)
                bf[n] = *(const s16x8*)(&vt[((ks * 4 + g) * 64 + n * 16 + r) * 8]);
            #pragma unroll
            for (int m = 0; m < 4; ++m)
                #pragma unroll
                for (int n = 0; n < 4; ++n)
                    acc[m][n] = __builtin_amdgcn_mfma_f32_16x16x32_bf16(
                        af[m], bf[n], acc[m][n], 0, 0, 0);
        }

        // epilogue: e-partial = sum tanh(U + hterm) * bw over this wave's betas
        float pe[4] = {0.f, 0.f, 0.f, 0.f};
        #pragma unroll
        for (int n = 0; n < 4; ++n) {
            const int b = n * 16 + r;
            #pragma unroll
            for (int m = 0; m < 4; ++m) {
                unsigned long long hv =
                    *(const unsigned long long*)(&ht[b * HTP + w * 64 + m * 16 + g * 4]);
                #pragma unroll
                for (int q = 0; q < 4; ++q) {
                    float x = acc[m][n][q] + bf2f((unsigned short)(hv >> (16 * q)));
                    float ex = __expf(x + x);
                    float t = 1.f - 2.f * __builtin_amdgcn_rcpf(1.f + ex);
                    pe[n] = fmaf(t, bw[m][q], pe[n]);
                }
            }
        }
        #pragma unroll
        for (int n = 0; n < 4; ++n) {
            pe[n] += __shfl_xor(pe[n], 16, 64);
            pe[n] += __shfl_xor(pe[n], 32, 64);
        }
        if (l < 16) {
            #pragma unroll
            for (int n = 0; n < 4; ++n) ew[w][n * 16 + l] = pe[n];
        }

        // write next-position staged tile (loads have had MFMA phase to land)
        if (pf) {
            #pragma unroll
            for (int rr = 0; rr < 4; ++rr) {
                s16x8 pk;
                #pragma unroll
                for (int j = 0; j < 8; ++j) pk[j] = (short)f2bf(nv[rr * 8 + j]);
                *(s16x8*)(&Vt[cur ^ 1][((rr * 8 + w) * 64 + l) * 8]) = pk;
            }
        }

        __syncthreads();  // ew complete; Vt[cur^1] complete

        // weight + accumulate: thread handles b=l, c in [w*32, w*32+32)
        float e = bbias;
        #pragma unroll
        for (int wv = 0; wv < 8; ++wv) e += ew[wv][l];
        float wgt = __expf(e);
        lacc += wgt;
        #pragma unroll
        for (int k = 0; k < 4; ++k) {
            s16x8 v = *(const s16x8*)(&vt[((w * 4 + k) * 64 + l) * 8]);
            #pragma unroll
            for (int j = 0; j < 8; ++j)
                cacc[k * 8 + j] = fmaf(wgt, bf2f((unsigned short)v[j]), cacc[k * 8 + j]);
        }
        __syncthreads();  // Vt[cur] reads done before next iter overwrites
    }

    float* np = num + blockIdx.x * (NB * CD) + l * CD + w * 32;
    #pragma unroll
    for (int k = 0; k < 8; ++k)
        *(f32x4*)(np + k * 4) =
            (f32x4){cacc[k * 4], cacc[k * 4 + 1], cacc[k * 4 + 2], cacc[k * 4 + 3]};
    if (tid < 64) lsum[blockIdx.x * NB + tid] = lacc;
}

// ---------------------------------------------------------------------------
// Combine: out[b][c] = sum_blk num[blk][b][c] / sum_blk lsum[blk][b]
// ---------------------------------------------------------------------------
__global__ __launch_bounds__(256) void combine_kernel(
    const float* __restrict__ num, const float* __restrict__ lsum,
    float* __restrict__ out)
{
    const int b = blockIdx.x, c = threadIdx.x;
    float s0 = 0.f, s1 = 0.f, s2 = 0.f, s3 = 0.f, ls = 0.f;
    #pragma unroll 4
    for (int k = 0; k < NBLK; k += 4) {
        s0 += num[(k + 0) * (NB * CD) + b * CD + c];
        s1 += num[(k + 1) * (NB * CD) + b * CD + c];
        s2 += num[(k + 2) * (NB * CD) + b * CD + c];
        s3 += num[(k + 3) * (NB * CD) + b * CD + c];
        ls += lsum[(k + 0) * NB + b] + lsum[(k + 1) * NB + b] +
              lsum[(k + 2) * NB + b] + lsum[(k + 3) * NB + b];
    }
    out[b * CD + c] = (s0 + s1 + s2 + s3) / ls;
}

extern "C" void kernel_launch(void* const* d_in, const int* in_sizes, int n_in,
                              void* d_out, int out_size, void* d_ws, size_t ws_size,
                              hipStream_t stream)
{
    (void)in_sizes; (void)n_in; (void)out_size; (void)ws_size;
    const float* V      = (const float*)d_in[0];
    const float* h_t    = (const float*)d_in[1];
    const float* W_h_w  = (const float*)d_in[2];
    const float* W_h_b  = (const float*)d_in[3];
    const float* W_w    = (const float*)d_in[4];
    const float* W_b    = (const float*)d_in[5];
    const float* beta_w = (const float*)d_in[6];
    const float* beta_b = (const float*)d_in[7];

    char* ws = (char*)d_ws;
    unsigned short* wwb = (unsigned short*)ws;                        // 256 KB
    unsigned short* hws = (unsigned short*)(ws + 262144);             // 64 KB
    float* num = (float*)(ws + 262144 + 65536);                       // 16 MB
    float* lsm = (float*)(ws + 262144 + 65536 + 16777216);            // 64 KB

    hipLaunchKernelGGL(prep_kernel, dim3(96), dim3(512), 0, stream,
                       h_t, W_h_w, W_h_b, W_w, W_b, hws, wwb);
    hipLaunchKernelGGL(attn_main, dim3(NBLK), dim3(512), 0, stream,
                       V, wwb, hws, beta_w, beta_b, num, lsm);
    hipLaunchKernelGGL(combine_kernel, dim3(64), dim3(256), 0, stream,
                       num, lsm, (float*)d_out);
}

// Round 3
// 313.884 us; speedup vs baseline: 1.6108x; 1.6108x over previous
//
#include <hip/hip_runtime.h>

typedef float f32x4 __attribute__((ext_vector_type(4)));
typedef short s16x8 __attribute__((ext_vector_type(8)));
typedef unsigned int u32;
typedef unsigned long long u64;
typedef unsigned short ush;

#define CD    256
#define NB    64
#define NBETA 512
#define NHID  512
#define PPB   16
#define NPC   256

__device__ __forceinline__ ush f2bf(float x) {
    u32 u = __builtin_bit_cast(u32, x);
    u += 0x7fffu + ((u >> 16) & 1u);
    return (ush)(u >> 16);
}
__device__ __forceinline__ float bf2f(ush h) {
    u32 u = ((u32)h) << 16;
    return __builtin_bit_cast(float, u);
}

// ---------------------------------------------------------------------------
// Prep: hterm[b][beta] = h_t[b]·W_h_w[beta] + W_h_b[beta] + W_b[beta] (bf16)
//       wwb = bf16(W_w)  [512][256]
// ---------------------------------------------------------------------------
__global__ __launch_bounds__(512) void prep_kernel(
    const float* __restrict__ h_t, const float* __restrict__ W_h_w,
    const float* __restrict__ W_h_b, const float* __restrict__ W_w,
    const float* __restrict__ W_b,
    ush* __restrict__ hws, ush* __restrict__ wwb)
{
    const int blk = blockIdx.x;
    const int tid = threadIdx.x;
    if (blk < NB) {
        __shared__ float hrow[NHID];
        hrow[tid] = h_t[blk * NHID + tid];
        __syncthreads();
        const float* wr = W_h_w + tid * NHID;
        float acc = W_h_b[tid] + W_b[tid];
        #pragma unroll 4
        for (int h = 0; h < NHID; h += 4) {
            f32x4 wv = *(const f32x4*)(wr + h);
            acc += wv.x * hrow[h] + wv.y * hrow[h + 1] +
                   wv.z * hrow[h + 2] + wv.w * hrow[h + 3];
        }
        hws[blk * NBETA + tid] = f2bf(acc);
    } else {
        const int idx = ((blk - NB) * 512 + tid) * 8;
        f32x4 a = *(const f32x4*)(W_w + idx);
        f32x4 b = *(const f32x4*)(W_w + idx + 4);
        s16x8 pk;
        pk[0] = (short)f2bf(a.x); pk[1] = (short)f2bf(a.y);
        pk[2] = (short)f2bf(a.z); pk[3] = (short)f2bf(a.w);
        pk[4] = (short)f2bf(b.x); pk[5] = (short)f2bf(b.y);
        pk[6] = (short)f2bf(b.z); pk[7] = (short)f2bf(b.w);
        *(s16x8*)(wwb + idx) = pk;
    }
}

// ---------------------------------------------------------------------------
// Main: block = (b-half of 32) x (16 positions). 8 waves, each owns a 64-beta
// slice. Per position: U[beta][b] = W_w@V + hterm (acc-init from LDS),
// e[b] = sum tanh(U)*bw -> wgt = exp(e); cacc += wgt*V from LDS.
// ---------------------------------------------------------------------------
__global__ __launch_bounds__(512, 4) void attn_main(
    const float* __restrict__ V,
    const ush* __restrict__ wwb,
    const ush* __restrict__ hws,
    const float* __restrict__ beta_w,
    const float* __restrict__ beta_b,
    float* __restrict__ num,
    float* __restrict__ lsum)
{
    __shared__ __align__(16) char VtB[2][16384];  // [32 b][256 c] bf16, swizzled
    __shared__ __align__(16) char htB[32768];     // [32 b][512 beta] bf16, swizzled
    __shared__ float ew[8][32];

    const int tid = threadIdx.x;
    const int l = tid & 63, w = tid >> 6, g = l >> 4, r = l & 15;
    const int bh = blockIdx.x & 1;
    const int bl = tid & 31, cg = tid >> 5;

    // hterm -> LDS: thread (bl,cg) covers betas [cg*32, cg*32+32) of row bl.
    // 8-byte-granule XOR swizzle by (row&7).  (Round-2 bug: only 16 betas
    // per thread were loaded -> upper half of each row was garbage -> NaN.)
    {
        const ush* src = hws + (bh * 32 + bl) * NBETA + cg * 32;
        const int swz = (bl & 7) << 3;
        char* dst = htB + bl * 1024;
        #pragma unroll
        for (int k = 0; k < 8; ++k)
            *(u64*)(dst + ((cg * 64 + k * 8) ^ swz)) = *(const u64*)(src + k * 4);
    }

    f32x4 bw[4];
    #pragma unroll
    for (int m = 0; m < 4; ++m)
        bw[m] = *(const f32x4*)(beta_w + w * 64 + m * 16 + g * 4);
    const float bbias = beta_b[0];

    float cacc[16];
    #pragma unroll
    for (int j = 0; j < 16; ++j) cacc[j] = 0.f;
    float lacc = 0.f;

    const float* vbase = V + (size_t)(blockIdx.x >> 1) * PPB * (CD * NB) + bh * 32 + bl;
    const int vswz = (bl & 7) << 4;

    // prologue: stage position 0 into buffer 0
    {
        float nv[16];
        #pragma unroll
        for (int j = 0; j < 16; ++j)
            nv[j] = __builtin_nontemporal_load(vbase + (cg * 16 + j) * NB);
        char* db = VtB[0] + bl * 512;
        #pragma unroll
        for (int k = 0; k < 2; ++k) {
            s16x8 pk;
            #pragma unroll
            for (int j = 0; j < 8; ++j) pk[j] = (short)f2bf(nv[k * 8 + j]);
            *(s16x8*)(db + ((cg * 32 + k * 16) ^ vswz)) = pk;
        }
    }
    __syncthreads();

    const int xr3 = (r & 7) << 3;
    const int xr4 = (r & 7) << 4;

    for (int i = 0; i < PPB; ++i) {
        const char* vt = VtB[i & 1];
        const bool pf = (i + 1 < PPB);

        // acc init = hterm (beta = w*64+m*16+g*4+q, b = n*16+r)
        f32x4 acc[4][2];
        #pragma unroll
        for (int n = 0; n < 2; ++n) {
            const char* hrow = htB + (n * 16 + r) * 1024;
            #pragma unroll
            for (int m = 0; m < 4; ++m) {
                u64 h = *(const u64*)(hrow + ((w * 128 + m * 32 + g * 8) ^ xr3));
                acc[m][n] = (f32x4){bf2f((ush)h), bf2f((ush)(h >> 16)),
                                    bf2f((ush)(h >> 32)), bf2f((ush)(h >> 48))};
            }
        }

        // U += W_w @ V_p : M=512(beta) N=32(b) K=256(c)
        const ush* wrow = wwb + (w * 64 + r) * CD + g * 8;
        const char* vrow0 = vt + r * 512;
        #pragma unroll 2
        for (int ks = 0; ks < 8; ++ks) {
            const int off = ((ks << 6) | (g << 4)) ^ xr4;
            s16x8 b0 = *(const s16x8*)(vrow0 + off);
            s16x8 b1 = *(const s16x8*)(vrow0 + 8192 + off);
            #pragma unroll
            for (int m = 0; m < 4; ++m) {
                s16x8 a = *(const s16x8*)(wrow + m * (16 * CD) + ks * 32);
                acc[m][0] = __builtin_amdgcn_mfma_f32_16x16x32_bf16(a, b0, acc[m][0], 0, 0, 0);
                acc[m][1] = __builtin_amdgcn_mfma_f32_16x16x32_bf16(a, b1, acc[m][1], 0, 0, 0);
            }
        }

        // issue next-position V loads (latency hidden under tanh epilogue)
        float nv[16];
        if (pf) {
            const float* vp = vbase + (size_t)(i + 1) * (CD * NB);
            #pragma unroll
            for (int j = 0; j < 16; ++j)
                nv[j] = __builtin_nontemporal_load(vp + (cg * 16 + j) * NB);
        }

        // epilogue: pe_n = sum_{m,q} tanh(acc)*bw
        float pe0 = 0.f, pe1 = 0.f;
        #pragma unroll
        for (int m = 0; m < 4; ++m) {
            #pragma unroll
            for (int q = 0; q < 4; ++q) {
                float x0 = acc[m][0][q], x1 = acc[m][1][q];
                float t0 = 1.f - 2.f * __builtin_amdgcn_rcpf(1.f + __expf(x0 + x0));
                float t1 = 1.f - 2.f * __builtin_amdgcn_rcpf(1.f + __expf(x1 + x1));
                pe0 = fmaf(t0, bw[m][q], pe0);
                pe1 = fmaf(t1, bw[m][q], pe1);
            }
        }
        pe0 += __shfl_xor(pe0, 16, 64); pe0 += __shfl_xor(pe0, 32, 64);
        pe1 += __shfl_xor(pe1, 16, 64); pe1 += __shfl_xor(pe1, 32, 64);
        if (l < 16) { ew[w][l] = pe0; ew[w][16 + l] = pe1; }

        // write staged tile for next position
        if (pf) {
            char* db = VtB[(i + 1) & 1] + bl * 512;
            #pragma unroll
            for (int k = 0; k < 2; ++k) {
                s16x8 pk;
                #pragma unroll
                for (int j = 0; j < 8; ++j) pk[j] = (short)f2bf(nv[k * 8 + j]);
                *(s16x8*)(db + ((cg * 32 + k * 16) ^ vswz)) = pk;
            }
        }
        __syncthreads();

        // weight + accumulate (thread: b=bl, c in [cg*16, cg*16+16))
        float e = bbias;
        #pragma unroll
        for (int wv = 0; wv < 8; ++wv) e += ew[wv][bl];
        float wgt = __expf(e);
        lacc += wgt;
        const char* vb = vt + bl * 512;
        #pragma unroll
        for (int k = 0; k < 2; ++k) {
            s16x8 v = *(const s16x8*)(vb + ((cg * 32 + k * 16) ^ vswz));
            #pragma unroll
            for (int j = 0; j < 8; ++j)
                cacc[k * 8 + j] = fmaf(wgt, bf2f((ush)v[j]), cacc[k * 8 + j]);
        }
        __syncthreads();
    }

    float* np = num + (size_t)blockIdx.x * (32 * CD) + bl * CD + cg * 16;
    #pragma unroll
    for (int k = 0; k < 4; ++k)
        *(f32x4*)(np + k * 4) =
            (f32x4){cacc[k * 4], cacc[k * 4 + 1], cacc[k * 4 + 2], cacc[k * 4 + 3]};
    if (tid < 32) lsum[blockIdx.x * 32 + tid] = lacc;
}

// ---------------------------------------------------------------------------
// Combine: out[b][c] = sum_pc num[2*pc+bh][bl][c] / sum_pc lsum[2*pc+bh][bl]
// ---------------------------------------------------------------------------
__global__ __launch_bounds__(256) void combine_kernel(
    const float* __restrict__ num, const float* __restrict__ lsum,
    float* __restrict__ out)
{
    const int b = blockIdx.x, c = threadIdx.x;
    const int bh = b >> 5, bl = b & 31;
    float s0 = 0.f, s1 = 0.f, ls = 0.f;
    #pragma unroll 2
    for (int k = 0; k < NPC; k += 2) {
        const int blk0 = 2 * k + bh, blk1 = 2 * (k + 1) + bh;
        s0 += num[(size_t)blk0 * (32 * CD) + bl * CD + c];
        s1 += num[(size_t)blk1 * (32 * CD) + bl * CD + c];
        ls += lsum[blk0 * 32 + bl] + lsum[blk1 * 32 + bl];
    }
    out[b * CD + c] = (s0 + s1) / ls;
}

extern "C" void kernel_launch(void* const* d_in, const int* in_sizes, int n_in,
                              void* d_out, int out_size, void* d_ws, size_t ws_size,
                              hipStream_t stream)
{
    (void)in_sizes; (void)n_in; (void)out_size; (void)ws_size;
    const float* V      = (const float*)d_in[0];
    const float* h_t    = (const float*)d_in[1];
    const float* W_h_w  = (const float*)d_in[2];
    const float* W_h_b  = (const float*)d_in[3];
    const float* W_w    = (const float*)d_in[4];
    const float* W_b    = (const float*)d_in[5];
    const float* beta_w = (const float*)d_in[6];
    const float* beta_b = (const float*)d_in[7];

    char* ws = (char*)d_ws;
    ush* wwb = (ush*)ws;                                   // 256 KB
    ush* hws = (ush*)(ws + 262144);                        // 64 KB
    float* num = (float*)(ws + 262144 + 65536);            // 16.78 MB
    float* lsm = (float*)(ws + 262144 + 65536 + 16777216); // 64 KB

    hipLaunchKernelGGL(prep_kernel, dim3(96), dim3(512), 0, stream,
                       h_t, W_h_w, W_h_b, W_w, W_b, hws, wwb);
    hipLaunchKernelGGL(attn_main, dim3(512), dim3(512), 0, stream,
                       V, wwb, hws, beta_w, beta_b, num, lsm);
    hipLaunchKernelGGL(combine_kernel, dim3(64), dim3(256), 0, stream,
                       num, lsm, (float*)d_out);
}